// Round 13
// baseline (1222.486 us; speedup 1.0000x reference)
//
#include <hip/hip_runtime.h>
#include <cstdint>

#define MDIM 4096
#define NDIM 9216
#define KDIM 3072
#define NG   48            // K groups of 64 (int8 MFMA K-tiles)

#define QROWS 4
#define QB2 1024           // quant blocks (4 rows each)
#define WB 13824           // weight-unpack blocks
#define PB2 1152           // Blora blocks (9216*32/256)

#define SLOT 34816         // LDS ring slot: A 16K | B 16K | as 1K | ws 1K

typedef unsigned int u32;
typedef unsigned short u16;
typedef float f32x4 __attribute__((ext_vector_type(4)));
typedef int   i32x4 __attribute__((ext_vector_type(4)));
typedef __bf16 bf16x8 __attribute__((ext_vector_type(8)));

__device__ __forceinline__ u16 f2bf(float f) {
  u32 u = __float_as_uint(f);
  u32 r = u + 0x7fffu + ((u >> 16) & 1u);   // round-to-nearest-even
  return (u16)(r >> 16);
}

__device__ __forceinline__ float frcp(float f) { return __builtin_amdgcn_rcpf(f); }

__device__ __forceinline__ void gld_lds16(const void* g, void* l) {
  __builtin_amdgcn_global_load_lds((__attribute__((address_space(1))) void*)g,
                                   (__attribute__((address_space(3))) void*)l,
                                   16, 0, 0);
}

// ---------------- kernel 0: zero the split-K output region (n in [6144,7168)) ----------------
__global__ __launch_bounds__(256) void k_zero(float* __restrict__ out) {
  const int row = blockIdx.x;
  float4* p = (float4*)(out + (size_t)row * NDIM + 6144);
  p[threadIdx.x] = make_float4(0.f, 0.f, 0.f, 0.f);
}

// ---------------- kernel 1a: activation quant -> int8 q + ascale + lora_act(bf16) ----------------
__global__ __launch_bounds__(256) void k_quant(const float* __restrict__ x,
                        const float* __restrict__ lora_down, const float* __restrict__ smooth,
                        int8_t* __restrict__ Aq, float* __restrict__ Asc, u16* __restrict__ Alora) {
  __shared__ float xs_s[QROWS][KDIM];   // 48 KB
  __shared__ float part[64 * 32];       // 8 KB
  const int tid = threadIdx.x;
  const int m0 = blockIdx.x * QROWS;
  const int sub = tid & 15;

  #pragma unroll
  for (int r = 0; r < QROWS; ++r) {
    const float* xr = x + (size_t)(m0 + r) * KDIM;
    int8_t* arow = Aq + (size_t)(m0 + r) * KDIM;
    #pragma unroll
    for (int p = 0; p < 3; ++p) {
      int g = p * 16 + (tid >> 4);
      int k0 = g * 64 + sub * 4;
      float4 xv = *(const float4*)(xr + k0);
      float4 sv = *(const float4*)(smooth + k0);
      float a0 = xv.x * frcp(sv.x), a1 = xv.y * frcp(sv.y);
      float a2 = xv.z * frcp(sv.z), a3 = xv.w * frcp(sv.w);
      xs_s[r][k0+0] = a0; xs_s[r][k0+1] = a1; xs_s[r][k0+2] = a2; xs_s[r][k0+3] = a3;
      float am = fmaxf(fmaxf(fabsf(a0), fabsf(a1)), fmaxf(fabsf(a2), fabsf(a3)));
      am = fmaxf(am, __shfl_xor(am, 8, 16));
      am = fmaxf(am, __shfl_xor(am, 4, 16));
      am = fmaxf(am, __shfl_xor(am, 2, 16));
      am = fmaxf(am, __shfl_xor(am, 1, 16));
      float asc = fmaxf(am * (1.0f / 7.0f), 1e-8f);
      float iasc = frcp(asc);
      int q0 = (int)fminf(7.f, fmaxf(-8.f, rintf(a0 * iasc)));
      int q1 = (int)fminf(7.f, fmaxf(-8.f, rintf(a1 * iasc)));
      int q2 = (int)fminf(7.f, fmaxf(-8.f, rintf(a2 * iasc)));
      int q3 = (int)fminf(7.f, fmaxf(-8.f, rintf(a3 * iasc)));
      u32 pk = (u32)(q0 & 0xff) | ((u32)(q1 & 0xff) << 8) |
               ((u32)(q2 & 0xff) << 16) | ((u32)(q3 & 0xff) << 24);
      *(u32*)(arow + k0) = pk;
      if (sub == 0) Asc[(size_t)g * MDIM + (m0 + r)] = asc;
    }
  }
  __syncthreads();

  // lora_act[r][rk] = sum_k xs[r][k] * lora_down[k][rk]
  const int c  = tid >> 2;
  const int r8 = (tid & 3) * 8;
  float a[QROWS][8] = {};
  const float* lp = lora_down + (size_t)c * 32 + r8;
  #pragma unroll 2
  for (int i = 0; i < 48; ++i) {
    float4 l0 = *(const float4*)(lp);
    float4 l1 = *(const float4*)(lp + 4);
    #pragma unroll
    for (int r = 0; r < QROWS; ++r) {
      float xv = xs_s[r][i * 64 + c];
      a[r][0] = fmaf(xv, l0.x, a[r][0]); a[r][1] = fmaf(xv, l0.y, a[r][1]);
      a[r][2] = fmaf(xv, l0.z, a[r][2]); a[r][3] = fmaf(xv, l0.w, a[r][3]);
      a[r][4] = fmaf(xv, l1.x, a[r][4]); a[r][5] = fmaf(xv, l1.y, a[r][5]);
      a[r][6] = fmaf(xv, l1.z, a[r][6]); a[r][7] = fmaf(xv, l1.w, a[r][7]);
    }
    lp += 64 * 32;
  }
  #pragma unroll 1
  for (int r = 0; r < QROWS; ++r) {
    __syncthreads();
    *(float4*)(&part[c * 32 + r8])     = make_float4(a[r][0], a[r][1], a[r][2], a[r][3]);
    *(float4*)(&part[c * 32 + r8 + 4]) = make_float4(a[r][4], a[r][5], a[r][6], a[r][7]);
    __syncthreads();
    if (tid < 32) {
      float s = 0.f;
      #pragma unroll 8
      for (int cc = 0; cc < 64; ++cc) s += part[cc * 32 + tid];
      Alora[(size_t)(m0 + r) * 32 + tid] = f2bf(s);   // LORA_SCALE = 1.0
    }
  }
}

// ---------------- kernel 1b: int4 nibble unpack -> int8 + Blora ----------------
__global__ __launch_bounds__(256) void k_wdq(const u32* __restrict__ qw,
                        const float* __restrict__ lora_up,
                        int8_t* __restrict__ Bq, u16* __restrict__ Blora) {
  const int tid = threadIdx.x;
  int bid = blockIdx.x;

  if (bid >= WB) {
    int idx = (bid - WB) * 256 + tid;        // < 9216*32
    int n = idx >> 5, cc = idx & 31;
    Blora[(size_t)n * 32 + cc] = f2bf(lora_up[(size_t)n * 32 + cc]);
    return;
  }
  // per-block layout detect: int8 stored as sign-extended int32 (f=1) vs raw bytes (f=0)
  __shared__ int s_viol;
  u32 probe = qw[tid];
  bool ok = (probe >> 8) == ((probe & 0x80u) ? 0xffffffu : 0u);
  if (tid == 0) s_viol = 0;
  __syncthreads();
  if (!ok) atomicOr(&s_viol, 1);
  __syncthreads();
  const int f = (s_viol == 0);

  int idx = bid * 256 + tid;   // < 9216*384
  int n = idx / 384;
  int j = idx - n * 384;
  u32 w;
  if (f) {
    uint4 q4 = ((const uint4*)qw)[idx];
    w = (q4.x & 0xffu) | ((q4.y & 0xffu) << 8) | ((q4.z & 0xffu) << 16) | ((q4.w & 0xffu) << 24);
  } else {
    w = qw[idx];
  }
  u32 o[2];
  #pragma unroll
  for (int h = 0; h < 2; ++h) {
    int b0 = (int)((w >> (16 * h)) & 0xffu);
    int b1 = (int)((w >> (16 * h + 8)) & 0xffu);
    int l0 = (b0 << 28) >> 28, h0 = (b0 << 24) >> 28;
    int l1 = (b1 << 28) >> 28, h1 = (b1 << 24) >> 28;
    o[h] = (u32)(l0 & 0xff) | ((u32)(h0 & 0xff) << 8) | ((u32)(l1 & 0xff) << 16) | ((u32)(h1 & 0xff) << 24);
  }
  *(uint2*)(Bq + (size_t)n * KDIM + j * 8) = make_uint2(o[0], o[1]);
}

// ---------------- kernel 2: 256x256 int8 MFMA GEMM, exact per-group rescale ----------------
// R12 ring (4 slots, distance 3, counted per-wave vmcnt) on int8 K-groups of 64.
// Per group: 32 x mfma_i32_16x16x64_i8 (in 4 quadrants of 8 to bound iacc regs) then
// acc_f32 += (float)iacc * ascale[row,g] * wscale[g,col] -- EXACT vs reference (no bf16
// rounding of inputs). Scales staged per slot: as[256 rows] by wave 0, ws[256 cols] by
// wave 1 (waves 0/1: 5 loads/iter -> vmcnt(10); others 4 -> vmcnt(8); per-wave uniform).
// LDS slot: A 16K (int8, row-pair swizzle c^(pr&7)) | B 16K | as 1K | ws 1K = 34 KB.
// i8 frag layout (analog of bf16 16x16x32): lane holds row=lane&15, 16 K-contig bytes at
// k=(lane>>4)*16 -> same aoff/boff arithmetic as the verified bf16 scheme (byte-scaled).
// Lora: one trailing bf16 16x16x32 K-tile from Alora/Blora into the same f32 acc.
// mode 0: 512 tiles = 2 packed rounds (nt 24-27 skipped); mode 1: those 64 V-tiles
// split-K x4 (12 groups each) via unsafeAtomicAdd onto k_zero'd region; bias+lora on s==0.
__global__ __launch_bounds__(512) void k_gemm(const int8_t* __restrict__ Aq, const int8_t* __restrict__ Bq,
                                              const float* __restrict__ Asc, const float* __restrict__ wsc,
                                              const u16* __restrict__ Alora, const u16* __restrict__ Blora,
                                              const float* __restrict__ bias, const float* __restrict__ norm_q,
                                              const float* __restrict__ norm_k, const float* __restrict__ rot,
                                              float* __restrict__ out, const int mode) {
  extern __shared__ char ldsb[];   // 4 * SLOT = 139264 B
  const int tid  = threadIdx.x;
  const int lane = tid & 63;
  const int wave = tid >> 6;

  int mt, nt, g0, nk;
  if (mode == 0) {
    mt = blockIdx.y;
    int xx = blockIdx.x;
    nt = xx + ((xx >= 24) ? 4 : 0);
    g0 = 0; nk = NG;
  } else {
    int s = blockIdx.x;
    mt = blockIdx.y & 15;
    nt = 24 + (blockIdx.y >> 4);
    g0 = s * 12; nk = 12;
  }
  const int m0 = mt * 256;
  const int n0 = nt * 256;
  const int wm = (wave >> 2) * 128;
  const int wn = (wave & 3) * 64;
  const int lr = lane & 15;
  const int lq = lane >> 4;

  // ---- staging: 2 A + 2 B 16B-chunks per thread per group; scales by waves 0/1 ----
  const int8_t *pA0, *pA1, *pB0, *pB1;
  int dA0, dA1, dB0, dB1;
  int rA0, kA0, rA1, kA1, rB0, kB0, rB1, kB1;
  {
    auto geo = [&](int p, int& r, int& kc) {
      int pr = p >> 3, cs = p & 7;
      int c  = cs ^ (pr & 7);
      r  = pr * 2 + (c >> 2);
      kc = c & 3;
    };
    int p0 = tid, p1 = 512 + tid;
    geo(p0, rA0, kA0); geo(p1, rA1, kA1);
    rB0 = rA0; kB0 = kA0; rB1 = rA1; kB1 = kA1;
    pA0 = Aq + (size_t)(m0 + rA0) * KDIM + g0 * 64 + kA0 * 16;
    pA1 = Aq + (size_t)(m0 + rA1) * KDIM + g0 * 64 + kA1 * 16;
    pB0 = Bq + (size_t)(n0 + rB0) * KDIM + g0 * 64 + kB0 * 16;
    pB1 = Bq + (size_t)(n0 + rB1) * KDIM + g0 * 64 + kB1 * 16;
    dA0 = p0 * 16; dA1 = p1 * 16;
    dB0 = 16384 + p0 * 16; dB1 = 16384 + p1 * 16;
  }
  const float* pAs = Asc + (size_t)g0 * MDIM + m0 + lane * 4;
  const float* pWs = wsc + (size_t)g0 * NDIM + n0 + lane * 4;

  // ---- fragment byte offsets within a slot ----
  int aoff[8], boff[4];
  #pragma unroll
  for (int t = 0; t < 8; ++t) {
    int ra = wm + t * 16 + lr;
    int pr = ra >> 1, cc = (ra & 1) * 4 + lq;
    aoff[t] = pr * 128 + ((cc ^ (pr & 7)) * 16);
  }
  #pragma unroll
  for (int t = 0; t < 4; ++t) {
    int rb = wn + t * 16 + lr;
    int pr = rb >> 1, cc = (rb & 1) * 4 + lq;
    boff[t] = 16384 + pr * 128 + ((cc ^ (pr & 7)) * 16);
  }

  f32x4 acc[8][4] = {};

  // ---- prologue: stage groups g0..g0+2 into slots 0,1,2 ----
  #pragma unroll
  for (int s = 0; s < 3; ++s) {
    char* sl = ldsb + s * SLOT;
    gld_lds16(pA0, sl + dA0); gld_lds16(pA1, sl + dA1);
    gld_lds16(pB0, sl + dB0); gld_lds16(pB1, sl + dB1);
    pA0 += 64; pA1 += 64; pB0 += 64; pB1 += 64;
    if (wave == 0)      { gld_lds16(pAs, sl + 32768 + lane * 16); pAs += MDIM; }
    else if (wave == 1) { gld_lds16(pWs, sl + 33792 + lane * 16); pWs += NDIM; }
  }
  if (wave < 2) asm volatile("s_waitcnt vmcnt(10)" ::: "memory");
  else          asm volatile("s_waitcnt vmcnt(8)" ::: "memory");
  __builtin_amdgcn_s_barrier();
  asm volatile("" ::: "memory");

  #pragma unroll 1
  for (int kt = 0; kt < nk; ++kt) {
    const char* cur = ldsb + (kt & 3) * SLOT;
    char* stl = ldsb + ((kt + 3) & 3) * SLOT;
    const bool st = (kt < nk - 3);
    if (st) {
      gld_lds16(pA0, stl + dA0); gld_lds16(pA1, stl + dA1);
      gld_lds16(pB0, stl + dB0); gld_lds16(pB1, stl + dB1);
      pA0 += 64; pA1 += 64; pB0 += 64; pB1 += 64;
      if (wave == 0)      { gld_lds16(pAs, stl + 32768 + lane * 16); pAs += MDIM; }
      else if (wave == 1) { gld_lds16(pWs, stl + 33792 + lane * 16); pWs += NDIM; }
    }
    i32x4 bf[4]; float wsv[4];
    #pragma unroll
    for (int t = 0; t < 4; ++t) bf[t] = *(const i32x4*)(cur + boff[t]);
    #pragma unroll
    for (int t = 0; t < 4; ++t) wsv[t] = *(const float*)(cur + 33792 + (wn + t * 16 + lr) * 4);
    __builtin_amdgcn_s_setprio(1);
    #pragma unroll
    for (int tp = 0; tp < 4; ++tp) {
      i32x4 a0 = *(const i32x4*)(cur + aoff[2 * tp]);
      i32x4 a1 = *(const i32x4*)(cur + aoff[2 * tp + 1]);
      i32x4 ia0[4], ia1[4];
      #pragma unroll
      for (int tj = 0; tj < 4; ++tj)
        ia0[tj] = __builtin_amdgcn_mfma_i32_16x16x64_i8(a0, bf[tj], (i32x4){0,0,0,0}, 0, 0, 0);
      #pragma unroll
      for (int tj = 0; tj < 4; ++tj)
        ia1[tj] = __builtin_amdgcn_mfma_i32_16x16x64_i8(a1, bf[tj], (i32x4){0,0,0,0}, 0, 0, 0);
      f32x4 as0 = *(const f32x4*)(cur + 32768 + (wm + (2 * tp) * 16 + lq * 4) * 4);
      f32x4 as1 = *(const f32x4*)(cur + 32768 + (wm + (2 * tp + 1) * 16 + lq * 4) * 4);
      #pragma unroll
      for (int tj = 0; tj < 4; ++tj) {
        f32x4 aw0 = as0 * wsv[tj];
        f32x4 aw1 = as1 * wsv[tj];
        #pragma unroll
        for (int rg = 0; rg < 4; ++rg) {
          acc[2 * tp][tj][rg]     += (float)ia0[tj][rg] * aw0[rg];
          acc[2 * tp + 1][tj][rg] += (float)ia1[tj][rg] * aw1[rg];
        }
      }
    }
    __builtin_amdgcn_s_setprio(0);
    if (st) {
      if (wave < 2) asm volatile("s_waitcnt vmcnt(10)" ::: "memory");
      else          asm volatile("s_waitcnt vmcnt(8)" ::: "memory");
    } else {
      asm volatile("s_waitcnt vmcnt(0)" ::: "memory");
    }
    __builtin_amdgcn_s_barrier();
    asm volatile("" ::: "memory");
  }

  // ---- lora tail: one bf16 16x16x32 K-tile (rank 32) into the same acc ----
  if (mode == 0 || blockIdx.x == 0) {
    char* sl = ldsb;   // slot 0: all main-loop reads retired at the final barrier
    gld_lds16(Alora + (size_t)(m0 + rA0) * 32 + kA0 * 8, sl + dA0);
    gld_lds16(Alora + (size_t)(m0 + rA1) * 32 + kA1 * 8, sl + dA1);
    gld_lds16(Blora + (size_t)(n0 + rB0) * 32 + kB0 * 8, sl + dB0);
    gld_lds16(Blora + (size_t)(n0 + rB1) * 32 + kB1 * 8, sl + dB1);
    asm volatile("s_waitcnt vmcnt(0)" ::: "memory");
    __builtin_amdgcn_s_barrier();
    asm volatile("" ::: "memory");
    bf16x8 laf[8], lbf[4];
    #pragma unroll
    for (int t = 0; t < 8; ++t) laf[t] = *(const bf16x8*)(sl + aoff[t]);
    #pragma unroll
    for (int t = 0; t < 4; ++t) lbf[t] = *(const bf16x8*)(sl + boff[t]);
    #pragma unroll
    for (int ti = 0; ti < 8; ++ti)
      #pragma unroll
      for (int tj = 0; tj < 4; ++tj)
        acc[ti][tj] = __builtin_amdgcn_mfma_f32_16x16x32_bf16(laf[ti], lbf[tj], acc[ti][tj], 0, 0, 0);
  }

  // ---- epilogue.  C/D layout: col = lane&15, row = (lane>>4)*4 + reg ----
  const int sel = (nt >= 24) ? 2 : (nt >= 12 ? 1 : 0);
  const float bscale = (mode == 0 || blockIdx.x == 0) ? 1.0f : 0.0f;

  float bv[4];
  #pragma unroll
  for (int tj = 0; tj < 4; ++tj) bv[tj] = bias[n0 + wn + tj * 16 + lr] * bscale;
  #pragma unroll
  for (int ti = 0; ti < 8; ++ti)
    #pragma unroll
    for (int tj = 0; tj < 4; ++tj)
      #pragma unroll
      for (int rg = 0; rg < 4; ++rg)
        acc[ti][tj][rg] += bv[tj];

  if (sel == 2) {
    if (mode == 0) {
      #pragma unroll
      for (int tj = 0; tj < 4; ++tj) {
        int n = n0 + wn + tj * 16 + lr;
        #pragma unroll
        for (int ti = 0; ti < 8; ++ti) {
          int mr = m0 + wm + ti * 16 + lq * 4;
          #pragma unroll
          for (int rg = 0; rg < 4; ++rg)
            out[(size_t)(mr + rg) * NDIM + n] = acc[ti][tj][rg];
        }
      }
    } else {
      #pragma unroll
      for (int tj = 0; tj < 4; ++tj) {
        int n = n0 + wn + tj * 16 + lr;
        #pragma unroll
        for (int ti = 0; ti < 8; ++ti) {
          int mr = m0 + wm + ti * 16 + lq * 4;
          #pragma unroll
          for (int rg = 0; rg < 4; ++rg)
            unsafeAtomicAdd(&out[(size_t)(mr + rg) * NDIM + n], acc[ti][tj][rg]);
        }
      }
    }
    return;
  }

  // RMSNorm + RoPE (mode 0 only reaches here)
  __syncthreads();
  float* ssq = (float*)ldsb;
  #pragma unroll
  for (int ti = 0; ti < 8; ++ti) {
    float pr4[4];
    #pragma unroll
    for (int rg = 0; rg < 4; ++rg) {
      float s = 0.f;
      #pragma unroll
      for (int tj = 0; tj < 4; ++tj) s += acc[ti][tj][rg] * acc[ti][tj][rg];
      pr4[rg] = s;
    }
    #pragma unroll
    for (int off = 1; off < 16; off <<= 1)
      #pragma unroll
      for (int rg = 0; rg < 4; ++rg) pr4[rg] += __shfl_xor(pr4[rg], off);
    #pragma unroll
    for (int rg = 0; rg < 4; ++rg)
      if (lr == (ti & 3) * 4 + rg)
        ssq[(wn >> 6) * 256 + wm + ti * 16 + lq * 4 + rg] = pr4[rg];
  }
  __syncthreads();

  const float* nrm = sel ? norm_k : norm_q;
  float gm[4];
  #pragma unroll
  for (int tj = 0; tj < 4; ++tj) gm[tj] = nrm[(wn & 64) + tj * 16 + lr];
  const float2* rot2 = (const float2*)rot;
  const float sgn = (lr & 1) ? 1.0f : -1.0f;
  const int hb = (wn >> 7) * 512;

  #pragma unroll
  for (int ti = 0; ti < 8; ++ti) {
    #pragma unroll
    for (int rg = 0; rg < 4; ++rg) {
      int row = wm + ti * 16 + lq * 4 + rg;
      float tot = ssq[hb + row] + ssq[hb + 256 + row];
      float rs = rsqrtf(tot * (1.0f / 128.0f) + 1e-6f);
      int m = m0 + row;
      #pragma unroll
      for (int tj = 0; tj < 4; ++tj) {
        int nl = (wn & 64) + tj * 16 + lr;
        float v = acc[ti][tj][rg] * rs * gm[tj];
        float p = __shfl_xor(v, 1);
        float2 cs = rot2[(size_t)m * 64 + (nl >> 1)];
        out[(size_t)m * NDIM + n0 + wn + tj * 16 + lr] = v * cs.x + sgn * (p * cs.y);
      }
    }
  }
}

extern "C" void kernel_launch(void* const* d_in, const int* in_sizes, int n_in,
                              void* d_out, int out_size, void* d_ws, size_t ws_size,
                              hipStream_t stream) {
  const float* x         = (const float*)d_in[0];
  const u32*   qweight   = (const u32*)d_in[1];
  const float* wscales   = (const float*)d_in[2];
  const float* bias      = (const float*)d_in[3];
  const float* lora_down = (const float*)d_in[4];
  const float* lora_up   = (const float*)d_in[5];
  const float* smooth    = (const float*)d_in[6];
  const float* norm_q    = (const float*)d_in[7];
  const float* norm_k    = (const float*)d_in[8];
  const float* rot       = (const float*)d_in[9];
  float* out = (float*)d_out;

  char* W = (char*)d_ws;
  int8_t* Aq   = (int8_t*)W;                          // 4096*3072   = 12,582,912
  int8_t* Bq   = (int8_t*)(W + 12582912);             // 9216*3072   = 28,311,552
  float*  Asc  = (float*)(W + 40894464);              // 48*4096*4   =    786,432
  u16*    Alora= (u16*)(W + 41680896);                // 4096*32*2   =    262,144
  u16*    Blora= (u16*)(W + 41943040);                // 9216*32*2   =    589,824

  static bool attr_set = false;
  if (!attr_set) {
    hipFuncSetAttribute(reinterpret_cast<const void*>(k_gemm),
                        hipFuncAttributeMaxDynamicSharedMemorySize, 4 * SLOT);
    attr_set = true;
  }

  k_zero<<<4096, 256, 0, stream>>>(out);
  k_wdq<<<WB + PB2, 256, 0, stream>>>(qweight, lora_up, Bq, Blora);
  k_quant<<<QB2, 256, 0, stream>>>(x, lora_down, smooth, Aq, Asc, Alora);
  // mode 0: 512 tiles = 2 packed rounds (nt 24-27 skipped)
  k_gemm<<<dim3(32, 16), 512, 4 * SLOT, stream>>>(Aq, Bq, Asc, wscales, Alora, Blora,
                                                  bias, norm_q, norm_k, rot, out, 0);
  // mode 1: the 64 skipped V-tiles, split-K x4 (12 groups each)
  k_gemm<<<dim3(4, 64), 512, 4 * SLOT, stream>>>(Aq, Bq, Asc, wscales, Alora, Blora,
                                                 bias, norm_q, norm_k, rot, out, 1);
}